// Round 7
// baseline (162.302 us; speedup 1.0000x reference)
//
#include <hip/hip_runtime.h>
#include <math.h>

#define B_ 16
#define L_ 256
#define D_ 64

#define CHUNK 16
#define WARM  5                     // 4 needed (rows 0..31 exact), +1 margin
#define NCH   (L_ / CHUNK)

#define HPITCH 96                   // floats per slot = 24 quads (16B)
#define HSLOTS 63                   // slot 0 = x(t) row 63; slot 1+r = h(t-1) row r (r=0..61)
#define HBUF   (HSLOTS * HPITCH)    // 6048 floats
#define LDSF   (2 * HBUF)           // 12096 floats = 47.25 KB

// fast tanh via v_exp_f32: overflow/NaN-safe, ~1e-7 rel error (thr 1e-2)
__device__ __forceinline__ float ftanh(float x) {
    float ax = fabsf(x);
    float e  = __builtin_amdgcn_exp2f(-2.8853900818f * ax);   // e^{-2ax}
    float r  = (1.0f - e) * __builtin_amdgcn_rcpf(1.0f + e);
    return copysignf(r, x);
}

// DPP wave shifts with zero boundary fill (bound_ctrl=1)
__device__ __forceinline__ float dpp_shr1(float x) {
    int r = __builtin_amdgcn_update_dpp(0, __float_as_int(x), 0x138, 0xF, 0xF, true);
    return __int_as_float(r);
}
__device__ __forceinline__ float dpp_shl1(float x) {
    int r = __builtin_amdgcn_update_dpp(0, __float_as_int(x), 0x130, 0xF, 0xF, true);
    return __int_as_float(r);
}

// ---------------------------------------------------------------------------
// pass0: rows 0..31 for ALL (b,t) — depend only on x(t). Fully parallel,
// memory-bound. 32 rows/block, 8 cols/thread. Grid MUST be
// B*L*32*8/256 = 4096 blocks (R6 bug: launched 512 -> 7/8 poisoned).
__global__ __launch_bounds__(256) void pass0(const float* __restrict__ X,
                                             float* __restrict__ H,
                                             const float* __restrict__ Wl,
                                             const float* __restrict__ bl) {
    const int tid    = threadIdx.x;
    const int row_id = blockIdx.x * 32 + (tid >> 3);
    const int c0     = (tid & 7) << 3;
    const int i      = row_id & 31;
    const int bt     = row_id >> 5;                    // b*L + t
    const float* xb  = X + ((size_t)bt << 12);

    float w[9];
#pragma unroll
    for (int k = 0; k < 9; ++k) w[k] = Wl[k];
    float acc[8];
#pragma unroll
    for (int k = 0; k < 8; ++k) acc[k] = bl[0];
    const float4 z4 = make_float4(0.f, 0.f, 0.f, 0.f);

#pragma unroll
    for (int ki = 0; ki < 3; ++ki) {
        const int cr = 2 * i - 1 + ki;                 // -1..63
        const float* rp = xb + (cr << 6);
        const bool rv = (cr >= 0);
        const float4 v0 = (rv && c0 > 0)  ? *reinterpret_cast<const float4*>(rp + c0 - 4) : z4;
        const float4 v1 =  rv             ? *reinterpret_cast<const float4*>(rp + c0)     : z4;
        const float4 v2 =  rv             ? *reinterpret_cast<const float4*>(rp + c0 + 4) : z4;
        const float4 v3 = (rv && c0 < 56) ? *reinterpret_cast<const float4*>(rp + c0 + 8) : z4;
        const float g[16] = {v0.x,v0.y,v0.z,v0.w, v1.x,v1.y,v1.z,v1.w,
                             v2.x,v2.y,v2.z,v2.w, v3.x,v3.y,v3.z,v3.w};
        const float wa = w[ki*3], wb = w[ki*3+1], wc = w[ki*3+2];
#pragma unroll
        for (int k = 0; k < 8; ++k)
            acc[k] = fmaf(wa, g[k+3], fmaf(wb, g[k+4], fmaf(wc, g[k+5], acc[k])));
    }
    float o[8];
#pragma unroll
    for (int k = 0; k < 8; ++k) o[k] = ftanh(acc[k]);

    float* gd = H + ((size_t)bt << 12) + (i << 6) + c0;
    *reinterpret_cast<float4*>(gd)     = make_float4(o[0],o[1],o[2],o[3]);
    *reinterpret_cast<float4*>(gd + 4) = make_float4(o[4],o[5],o[6],o[7]);
}

// ---------------------------------------------------------------------------
// fused_tail: rows 32..62, serial over t per (b, chunk). Sources per step t:
//   slot 0      = x(t) row 63         (global X, prefetched)
//   slots 1..32 = h(t-1) rows 0..31   (global H, precomputed by pass0 — pure
//                                      streaming prefetch, off the chain)
//   slots 33..62= h(t-1) rows 32..61  (self, XOR-swizzled LDS double buffer)
// Data quad q of slot s lives at phys quad (q+1)^((s>>1)&7); quads phys v and
// 16+(1^v) are zero pads (init once). 5 warm-up steps make chunk starts exact
// (rows 0..31 exact from global, so level-k rows converge at tw+k-1, k<=5).
__global__ __launch_bounds__(256, 1) void fused_tail(
        const float* __restrict__ X, float* __restrict__ H,
        const float* __restrict__ Wl, const float* __restrict__ bl) {
    __shared__ float lds[LDSF];
    float* const hA = lds;
    float* const hB = lds + HBUF;

    const int tid  = threadIdx.x;
    const int b    = blockIdx.x >> 4;
    const int ch   = blockIdx.x & (NCH - 1);
    const int T0   = ch * CHUNK;
    const int tw   = (T0 >= WARM) ? (T0 - WARM) : 0;
    const int tend = T0 + CHUNK;

    // comp mapping: 248 threads -> rows 32..62, 8 cols each
    const bool comp = tid < 248;
    const int  i    = 32 + (tid >> 3);
    const int  c0   = (tid & 7) << 3;
    const int  q0   = c0 >> 2;

    // loader A mapping: all 256 threads -> slots 1..32 (h rows 0..31), 2 quads
    const int  sA = 1 + (tid >> 3);
    const int  qA = (tid & 7) * 2;
    const int  vA = (sA >> 1) & 7;
    // loader B mapping: threads 0..15 -> slot 0 (x row 63), 1 quad each
    const bool ldB = tid < 16;

    float w[9];
#pragma unroll
    for (int k = 0; k < 9; ++k) w[k] = Wl[k];
    const float bias = bl[0];
    const float4 z4 = make_float4(0.f, 0.f, 0.f, 0.f);

    for (int k = tid; k < LDSF / 4; k += 256)
        reinterpret_cast<float4*>(lds)[k] = z4;        // pads + h(-1)=0 + warm zeros
    __syncthreads();

    // initial stage for t = tw into hA
    if (tw > 0) {                                      // slots 1..32 <- h(tw-1) rows 0..31
        const float* hs = H + (((size_t)(b * L_ + tw - 1)) << 12) + ((sA - 1) << 6) + (qA << 2);
        const float4 a0 = *reinterpret_cast<const float4*>(hs);
        const float4 a1 = *reinterpret_cast<const float4*>(hs + 4);
        float* hd = hA + sA * HPITCH;
        *reinterpret_cast<float4*>(hd + (((qA + 1) ^ vA) << 2)) = a0;
        *reinterpret_cast<float4*>(hd + (((qA + 2) ^ vA) << 2)) = a1;
    }
    if (ldB) {                                         // slot 0 <- x(tw) row 63
        const float* xs = X + (((size_t)(b * L_ + tw)) << 12) + (63 << 6) + (tid << 2);
        *reinterpret_cast<float4*>(hA + ((tid + 1) << 2)) =
            *reinterpret_cast<const float4*>(xs);
    }
    __syncthreads();

    auto STEP = [&](int t, float* hcur, float* hnxt) {
        // issue next-step loads first (latency hides under compute)
        const int tn = (t + 1 < L_) ? t + 1 : L_ - 1;
        const float* hs = H + (((size_t)(b * L_ + t)) << 12) + ((sA - 1) << 6) + (qA << 2);
        const float4 la0 = *reinterpret_cast<const float4*>(hs);
        const float4 la1 = *reinterpret_cast<const float4*>(hs + 4);
        float4 lb = z4;
        if (ldB) {
            const float* xs = X + (((size_t)(b * L_ + tn)) << 12) + (63 << 6) + (tid << 2);
            lb = *reinterpret_cast<const float4*>(xs);
        }

        if (comp) {
            float acc[8];
#pragma unroll
            for (int k = 0; k < 8; ++k) acc[k] = bias;
#pragma unroll
            for (int ki = 0; ki < 3; ++ki) {
                const int s = 2 * i - 64 + ki;         // slot 0..62
                const int v = (s >> 1) & 7;
                const float* hb = hcur + s * HPITCH;
                float g[16];
#pragma unroll
                for (int k = 0; k < 4; ++k) {
                    const float4 t4 = *reinterpret_cast<const float4*>(
                        hb + (((q0 + k) ^ v) << 2));
                    g[k*4+0] = t4.x; g[k*4+1] = t4.y;
                    g[k*4+2] = t4.z; g[k*4+3] = t4.w;
                }
                const float wa = w[ki*3], wb = w[ki*3+1], wc = w[ki*3+2];
#pragma unroll
                for (int k = 0; k < 8; ++k)
                    acc[k] = fmaf(wa, g[k+3], fmaf(wb, g[k+4], fmaf(wc, g[k+5], acc[k])));
            }
            float o[8];
#pragma unroll
            for (int k = 0; k < 8; ++k) o[k] = ftanh(acc[k]);

            if (t >= T0) {
                float* gd = H + (((size_t)(b * L_ + t)) << 12) + (i << 6) + c0;
                *reinterpret_cast<float4*>(gd)     = make_float4(o[0],o[1],o[2],o[3]);
                *reinterpret_cast<float4*>(gd + 4) = make_float4(o[4],o[5],o[6],o[7]);
            }
            if (i <= 61) {                             // row 62 never re-read
                const int si = i + 1;
                const int vi = (si >> 1) & 7;
                float* hd = hnxt + si * HPITCH;
                *reinterpret_cast<float4*>(hd + (((q0+1) ^ vi) << 2)) =
                    make_float4(o[0],o[1],o[2],o[3]);
                *reinterpret_cast<float4*>(hd + (((q0+2) ^ vi) << 2)) =
                    make_float4(o[4],o[5],o[6],o[7]);
            }
        }
        {   // commit loader regs into hnxt
            float* hd = hnxt + sA * HPITCH;
            *reinterpret_cast<float4*>(hd + (((qA + 1) ^ vA) << 2)) = la0;
            *reinterpret_cast<float4*>(hd + (((qA + 2) ^ vA) << 2)) = la1;
            if (ldB)
                *reinterpret_cast<float4*>(hnxt + ((tid + 1) << 2)) = lb;
        }
        __syncthreads();
    };

    for (int t = tw; t < tend; t += 2) {               // block-uniform bounds
        STEP(t, hA, hB);
        if (t + 1 < tend) STEP(t + 1, hB, hA);
    }
}

// ---------------------------------------------------------------------------
// Sequential scan for row 63 (reads rows 61/62 from global, written by tail).
#define SDEPTH 16
__global__ void scan63(float* __restrict__ dst,
                       const float* __restrict__ src,
                       const float* __restrict__ Wl,
                       const float* __restrict__ bl) {
    const int b = blockIdx.x;
    const int j = threadIdx.x;                         // 0..63, one wave
    float w[9];
#pragma unroll
    for (int k = 0; k < 9; ++k) w[k] = Wl[k];
    const float bias = bl[0];

    const size_t ST = (size_t)D_ * D_;
    const float* s61 = src + (size_t)b * L_ * ST + 61 * 64 + j;
    const float* s62 = src + (size_t)b * L_ * ST + 62 * 64 + j;
    float*       d63 = dst + (size_t)b * L_ * ST + 63 * 64 + j;

    float s = ftanh(bias);                             // t=0: h_{-1}=0
    d63[0] = s;

    float p61[SDEPTH], p62[SDEPTH];
#pragma unroll
    for (int u = 0; u < SDEPTH; ++u) {
        p61[u] = s61[(size_t)u * ST];
        p62[u] = s62[(size_t)u * ST];
    }

    for (int t0 = 1; t0 < 256; t0 += SDEPTH) {
#pragma unroll
        for (int u = 0; u < SDEPTH; ++u) {
            const int t = t0 + u;
            if (t > 255) break;
            const float r61 = p61[u], r62 = p62[u];
            int tp = t + SDEPTH - 1;
            if (tp > 255) tp = 255;
            p61[u] = s61[(size_t)tp * ST];
            p62[u] = s62[(size_t)tp * ST];
            float l1 = dpp_shr1(r61), q1 = dpp_shl1(r61);
            float l2 = dpp_shr1(r62), q2 = dpp_shl1(r62);
            float p = bias;
            p = fmaf(w[0], l1, p); p = fmaf(w[1], r61, p); p = fmaf(w[2], q1, p);
            p = fmaf(w[3], l2, p); p = fmaf(w[4], r62, p); p = fmaf(w[5], q2, p);
            float ls = dpp_shr1(s), rs = dpp_shl1(s);
            float z = fmaf(w[6], ls, fmaf(w[7], s, fmaf(w[8], rs, p)));
            s = ftanh(z);
            d63[(size_t)t * ST] = s;
        }
    }
}

extern "C" void kernel_launch(void* const* d_in, const int* in_sizes, int n_in,
                              void* d_out, int out_size, void* d_ws, size_t ws_size,
                              hipStream_t stream) {
    const float* x    = (const float*)d_in[0];   // (B,L,D,D)
    const float* W    = (const float*)d_in[1];   // (2,1,1,3,3)
    const float* bias = (const float*)d_in[2];   // (2,)
    float* out = (float*)d_out;
    float* h1  = (float*)d_ws;

    // pass0 grid: B*L*32 rows * 8 threads/row / 256 threads/block = 4096
    const int P0_BLOCKS = (B_ * L_ * 32 * 8) / 256;

    for (int l = 0; l < 2; ++l) {
        const float* X  = (l == 0) ? x  : h1;
        float*       H  = (l == 0) ? h1 : out;
        pass0<<<P0_BLOCKS, 256, 0, stream>>>(X, H, W + l * 9, bias + l);
        fused_tail<<<B_ * NCH, 256, 0, stream>>>(X, H, W + l * 9, bias + l);
        scan63<<<B_, 64, 0, stream>>>(H, H, W + l * 9, bias + l);
    }
}

// Round 9
// 135.277 us; speedup vs baseline: 1.1998x; 1.1998x over previous
//
#include <hip/hip_runtime.h>
#include <math.h>

#define B_ 16
#define L_ 256
#define D_ 64

#define CHUNK 16
#define WARM  5                     // 4 needed (rows 0..31 exact), +1 margin
#define NCH   (L_ / CHUNK)

#define HPITCH 96                   // fused_tail: floats per slot = 24 quads
#define HSLOTS 63
#define HBUF   (HSLOTS * HPITCH)
#define LDSF   (2 * HBUF)           // 47.25 KB

#define P0PITCH 96                  // pass0: 24 quads/slot — swizzle (dq+1)^v reaches 23!
                                    // (R8 bug: 72 = 18 quads overflowed into neighbors)
#define P0SLOTS 65                  // slot 0 = zeros (row -1); slot 1+r = x row r
#define P0LDS   (P0SLOTS * P0PITCH) // 6240 floats = 24.4 KB

// fast tanh via v_exp_f32: overflow/NaN-safe, ~1e-7 rel error (thr 1e-2)
__device__ __forceinline__ float ftanh(float x) {
    float ax = fabsf(x);
    float e  = __builtin_amdgcn_exp2f(-2.8853900818f * ax);   // e^{-2ax}
    float r  = (1.0f - e) * __builtin_amdgcn_rcpf(1.0f + e);
    return copysignf(r, x);
}

// DPP wave shifts with zero boundary fill (bound_ctrl=1)
__device__ __forceinline__ float dpp_shr1(float x) {
    int r = __builtin_amdgcn_update_dpp(0, __float_as_int(x), 0x138, 0xF, 0xF, true);
    return __int_as_float(r);
}
__device__ __forceinline__ float dpp_shl1(float x) {
    int r = __builtin_amdgcn_update_dpp(0, __float_as_int(x), 0x130, 0xF, 0xF, true);
    return __int_as_float(r);
}

// ---------------------------------------------------------------------------
// pass0 v2: rows 0..31 for ALL (b,t). Block = one (b,t) frame. Stage the
// 16 KB x-frame into XOR-swizzled LDS with WAVE-CONTIGUOUS global loads
// (R7 lesson: scattered-window reads cap at ~1.7 TB/s; contiguous ~6 TB/s).
// Data quad dq of slot s lives at phys quad (dq+1)^((s>>1)&7) — range 0..23,
// so pitch MUST be 24 quads. Phys quads 0^v and 17^v stay zero (pads).
__global__ __launch_bounds__(256) void pass0(const float* __restrict__ X,
                                             float* __restrict__ H,
                                             const float* __restrict__ Wl,
                                             const float* __restrict__ bl) {
    __shared__ float xs[P0LDS];
    const int tid = threadIdx.x;
    const int bt  = blockIdx.x;                        // b*L + t

    float w[9];
#pragma unroll
    for (int k = 0; k < 9; ++k) w[k] = Wl[k];
    const float bias = bl[0];
    const float4 z4 = make_float4(0.f, 0.f, 0.f, 0.f);

    // zero whole LDS frame (covers pads + slot 0)
    for (int k = tid; k < P0LDS / 4; k += 256)
        reinterpret_cast<float4*>(xs)[k] = z4;
    __syncthreads();

    // stage: thread t holds frame floats [16t, 16t+16) -> row r = t>>2,
    // data quads 4*(t&3) .. +3. Global reads fully contiguous per wave.
    {
        const float* xg = X + ((size_t)bt << 12) + (tid << 4);
        float4 a[4];
#pragma unroll
        for (int k = 0; k < 4; ++k)
            a[k] = reinterpret_cast<const float4*>(xg)[k];
        const int r  = tid >> 2;
        const int s  = r + 1;
        const int v  = (s >> 1) & 7;
        const int bq = (tid & 3) << 2;
        float* dst = xs + s * P0PITCH;
#pragma unroll
        for (int k = 0; k < 4; ++k)
            *reinterpret_cast<float4*>(dst + (((bq + k + 1) ^ v) << 2)) = a[k];
    }
    __syncthreads();

    // compute: i = tid>>3 (0..31), 8 cols per thread
    const int i  = tid >> 3;
    const int c0 = (tid & 7) << 3;
    const int q0 = c0 >> 2;

    float acc[8];
#pragma unroll
    for (int k = 0; k < 8; ++k) acc[k] = bias;
#pragma unroll
    for (int ki = 0; ki < 3; ++ki) {
        const int s = 2 * i + ki;                      // slot for row 2i-1+ki
        const int v = (s >> 1) & 7;
        const float* hb = xs + s * P0PITCH;
        float g[16];
#pragma unroll
        for (int k = 0; k < 4; ++k) {                  // data quads q0-1..q0+2
            const float4 t4 = *reinterpret_cast<const float4*>(
                hb + (((q0 + k) ^ v) << 2));
            g[k*4+0] = t4.x; g[k*4+1] = t4.y;
            g[k*4+2] = t4.z; g[k*4+3] = t4.w;
        }
        const float wa = w[ki*3], wb = w[ki*3+1], wc = w[ki*3+2];
#pragma unroll
        for (int k = 0; k < 8; ++k)
            acc[k] = fmaf(wa, g[k+3], fmaf(wb, g[k+4], fmaf(wc, g[k+5], acc[k])));
    }
    float o[8];
#pragma unroll
    for (int k = 0; k < 8; ++k) o[k] = ftanh(acc[k]);

    float* gd = H + ((size_t)bt << 12) + (i << 6) + c0;
    *reinterpret_cast<float4*>(gd)     = make_float4(o[0],o[1],o[2],o[3]);
    *reinterpret_cast<float4*>(gd + 4) = make_float4(o[4],o[5],o[6],o[7]);
}

// ---------------------------------------------------------------------------
// fused_tail: rows 32..62, serial over t per (b, chunk). Sources per step t:
//   slot 0      = x(t) row 63         (global X, prefetched)
//   slots 1..32 = h(t-1) rows 0..31   (global H from pass0, streaming prefetch)
//   slots 33..62= h(t-1) rows 32..61  (self, XOR-swizzled LDS double buffer)
// Data quad q of slot s lives at phys quad (q+1)^((s>>1)&7). 5 warm-up steps
// make chunk starts exact (level-k rows converge at tw+k-1, k<=5).
__global__ __launch_bounds__(256, 1) void fused_tail(
        const float* __restrict__ X, float* __restrict__ H,
        const float* __restrict__ Wl, const float* __restrict__ bl) {
    __shared__ float lds[LDSF];
    float* const hA = lds;
    float* const hB = lds + HBUF;

    const int tid  = threadIdx.x;
    const int b    = blockIdx.x >> 4;
    const int ch   = blockIdx.x & (NCH - 1);
    const int T0   = ch * CHUNK;
    const int tw   = (T0 >= WARM) ? (T0 - WARM) : 0;
    const int tend = T0 + CHUNK;

    const bool comp = tid < 248;                       // rows 32..62
    const int  i    = 32 + (tid >> 3);
    const int  c0   = (tid & 7) << 3;
    const int  q0   = c0 >> 2;

    const int  sA = 1 + (tid >> 3);                    // loader A: slots 1..32
    const int  qA = (tid & 7) * 2;
    const int  vA = (sA >> 1) & 7;
    const bool ldB = tid < 16;                         // loader B: slot 0

    float w[9];
#pragma unroll
    for (int k = 0; k < 9; ++k) w[k] = Wl[k];
    const float bias = bl[0];
    const float4 z4 = make_float4(0.f, 0.f, 0.f, 0.f);

    for (int k = tid; k < LDSF / 4; k += 256)
        reinterpret_cast<float4*>(lds)[k] = z4;
    __syncthreads();

    if (tw > 0) {
        const float* hs = H + (((size_t)(b * L_ + tw - 1)) << 12) + ((sA - 1) << 6) + (qA << 2);
        const float4 a0 = *reinterpret_cast<const float4*>(hs);
        const float4 a1 = *reinterpret_cast<const float4*>(hs + 4);
        float* hd = hA + sA * HPITCH;
        *reinterpret_cast<float4*>(hd + (((qA + 1) ^ vA) << 2)) = a0;
        *reinterpret_cast<float4*>(hd + (((qA + 2) ^ vA) << 2)) = a1;
    }
    if (ldB) {
        const float* xs = X + (((size_t)(b * L_ + tw)) << 12) + (63 << 6) + (tid << 2);
        *reinterpret_cast<float4*>(hA + ((tid + 1) << 2)) =
            *reinterpret_cast<const float4*>(xs);
    }
    __syncthreads();

    auto STEP = [&](int t, float* hcur, float* hnxt) {
        const int tn = (t + 1 < L_) ? t + 1 : L_ - 1;
        const float* hs = H + (((size_t)(b * L_ + t)) << 12) + ((sA - 1) << 6) + (qA << 2);
        const float4 la0 = *reinterpret_cast<const float4*>(hs);
        const float4 la1 = *reinterpret_cast<const float4*>(hs + 4);
        float4 lb = z4;
        if (ldB) {
            const float* xs = X + (((size_t)(b * L_ + tn)) << 12) + (63 << 6) + (tid << 2);
            lb = *reinterpret_cast<const float4*>(xs);
        }

        if (comp) {
            float acc[8];
#pragma unroll
            for (int k = 0; k < 8; ++k) acc[k] = bias;
#pragma unroll
            for (int ki = 0; ki < 3; ++ki) {
                const int s = 2 * i - 64 + ki;
                const int v = (s >> 1) & 7;
                const float* hb = hcur + s * HPITCH;
                float g[16];
#pragma unroll
                for (int k = 0; k < 4; ++k) {
                    const float4 t4 = *reinterpret_cast<const float4*>(
                        hb + (((q0 + k) ^ v) << 2));
                    g[k*4+0] = t4.x; g[k*4+1] = t4.y;
                    g[k*4+2] = t4.z; g[k*4+3] = t4.w;
                }
                const float wa = w[ki*3], wb = w[ki*3+1], wc = w[ki*3+2];
#pragma unroll
                for (int k = 0; k < 8; ++k)
                    acc[k] = fmaf(wa, g[k+3], fmaf(wb, g[k+4], fmaf(wc, g[k+5], acc[k])));
            }
            float o[8];
#pragma unroll
            for (int k = 0; k < 8; ++k) o[k] = ftanh(acc[k]);

            if (t >= T0) {
                float* gd = H + (((size_t)(b * L_ + t)) << 12) + (i << 6) + c0;
                *reinterpret_cast<float4*>(gd)     = make_float4(o[0],o[1],o[2],o[3]);
                *reinterpret_cast<float4*>(gd + 4) = make_float4(o[4],o[5],o[6],o[7]);
            }
            if (i <= 61) {
                const int si = i + 1;
                const int vi = (si >> 1) & 7;
                float* hd = hnxt + si * HPITCH;
                *reinterpret_cast<float4*>(hd + (((q0+1) ^ vi) << 2)) =
                    make_float4(o[0],o[1],o[2],o[3]);
                *reinterpret_cast<float4*>(hd + (((q0+2) ^ vi) << 2)) =
                    make_float4(o[4],o[5],o[6],o[7]);
            }
        }
        {
            float* hd = hnxt + sA * HPITCH;
            *reinterpret_cast<float4*>(hd + (((qA + 1) ^ vA) << 2)) = la0;
            *reinterpret_cast<float4*>(hd + (((qA + 2) ^ vA) << 2)) = la1;
            if (ldB)
                *reinterpret_cast<float4*>(hnxt + ((tid + 1) << 2)) = lb;
        }
        __syncthreads();
    };

    for (int t = tw; t < tend; t += 2) {
        STEP(t, hA, hB);
        if (t + 1 < tend) STEP(t + 1, hB, hA);
    }
}

// ---------------------------------------------------------------------------
// Sequential scan for row 63 (reads rows 61/62 from global, written by tail).
#define SDEPTH 16
__global__ void scan63(float* __restrict__ dst,
                       const float* __restrict__ src,
                       const float* __restrict__ Wl,
                       const float* __restrict__ bl) {
    const int b = blockIdx.x;
    const int j = threadIdx.x;
    float w[9];
#pragma unroll
    for (int k = 0; k < 9; ++k) w[k] = Wl[k];
    const float bias = bl[0];

    const size_t ST = (size_t)D_ * D_;
    const float* s61 = src + (size_t)b * L_ * ST + 61 * 64 + j;
    const float* s62 = src + (size_t)b * L_ * ST + 62 * 64 + j;
    float*       d63 = dst + (size_t)b * L_ * ST + 63 * 64 + j;

    float s = ftanh(bias);
    d63[0] = s;

    float p61[SDEPTH], p62[SDEPTH];
#pragma unroll
    for (int u = 0; u < SDEPTH; ++u) {
        p61[u] = s61[(size_t)u * ST];
        p62[u] = s62[(size_t)u * ST];
    }

    for (int t0 = 1; t0 < 256; t0 += SDEPTH) {
#pragma unroll
        for (int u = 0; u < SDEPTH; ++u) {
            const int t = t0 + u;
            if (t > 255) break;
            const float r61 = p61[u], r62 = p62[u];
            int tp = t + SDEPTH - 1;
            if (tp > 255) tp = 255;
            p61[u] = s61[(size_t)tp * ST];
            p62[u] = s62[(size_t)tp * ST];
            float l1 = dpp_shr1(r61), q1 = dpp_shl1(r61);
            float l2 = dpp_shr1(r62), q2 = dpp_shl1(r62);
            float p = bias;
            p = fmaf(w[0], l1, p); p = fmaf(w[1], r61, p); p = fmaf(w[2], q1, p);
            p = fmaf(w[3], l2, p); p = fmaf(w[4], r62, p); p = fmaf(w[5], q2, p);
            float ls = dpp_shr1(s), rs = dpp_shl1(s);
            float z = fmaf(w[6], ls, fmaf(w[7], s, fmaf(w[8], rs, p)));
            s = ftanh(z);
            d63[(size_t)t * ST] = s;
        }
    }
}

extern "C" void kernel_launch(void* const* d_in, const int* in_sizes, int n_in,
                              void* d_out, int out_size, void* d_ws, size_t ws_size,
                              hipStream_t stream) {
    const float* x    = (const float*)d_in[0];   // (B,L,D,D)
    const float* W    = (const float*)d_in[1];   // (2,1,1,3,3)
    const float* bias = (const float*)d_in[2];   // (2,)
    float* out = (float*)d_out;
    float* h1  = (float*)d_ws;

    for (int l = 0; l < 2; ++l) {
        const float* X  = (l == 0) ? x  : h1;
        float*       H  = (l == 0) ? h1 : out;
        pass0<<<B_ * L_, 256, 0, stream>>>(X, H, W + l * 9, bias + l);   // 1 block = 1 frame
        fused_tail<<<B_ * NCH, 256, 0, stream>>>(X, H, W + l * 9, bias + l);
        scan63<<<B_, 64, 0, stream>>>(H, H, W + l * 9, bias + l);
    }
}

// Round 10
// 122.771 us; speedup vs baseline: 1.3220x; 1.1019x over previous
//
#include <hip/hip_runtime.h>
#include <math.h>

#define B_ 16
#define L_ 256
#define D_ 64

#define CHUNK 16
#define WARM  6                     // row 62 exact at tw+5; +1 margin
#define NCH   (L_ / CHUNK)

#define PITCH 96                    // 24 quads/slot: swizzle (dq+1)^v reaches 23 (R8 lesson)
#define NSLOT 127                   // slot 0 = zeros (concat row -1); 1..64 = x rows 0..63;
                                    // 65..126 = h(t-1) rows 0..61
#define FBUF  (NSLOT * PITCH)       // 12192 floats
#define LDSZ  (2 * FBUF)            // 24384 floats = 95.25 KB (1 block/CU)

// fast tanh via v_exp_f32: overflow/NaN-safe, ~1e-7 rel error (thr 1e-2)
__device__ __forceinline__ float ftanh(float x) {
    float ax = fabsf(x);
    float e  = __builtin_amdgcn_exp2f(-2.8853900818f * ax);   // e^{-2ax}
    float r  = (1.0f - e) * __builtin_amdgcn_rcpf(1.0f + e);
    return copysignf(r, x);
}

// DPP wave shifts with zero boundary fill (bound_ctrl=1)
__device__ __forceinline__ float dpp_shr1(float x) {
    int r = __builtin_amdgcn_update_dpp(0, __float_as_int(x), 0x138, 0xF, 0xF, true);
    return __int_as_float(r);
}
__device__ __forceinline__ float dpp_shl1(float x) {
    int r = __builtin_amdgcn_update_dpp(0, __float_as_int(x), 0x130, 0xF, 0xF, true);
    return __int_as_float(r);
}

// ---------------------------------------------------------------------------
// fused_layer: rows 0..62 for a (b, t-chunk), serial over t. ONE kernel does
// what pass0+fused_tail did: the full x(t) frame is staged into XOR-swizzled
// LDS (wave-contiguous global reads, 2-step register prefetch), h(t-1) rows
// 0..61 live in the same double-buffered LDS frame. Rows 0..31 are recomputed
// from x each step (VALU is idle anyway) instead of round-tripping via global.
// Slot s holds concat row s-1; data quad dq of slot s at phys quad
// (dq+1)^((s>>1)&7); phys 0^v and 17^v are zero pads. WARM=6 warm-up steps
// make chunk starts exact (level-k rows converge at tw+k, k<=5).
// Row 63 (truly recurrent) is finished by scan63.
__global__ __launch_bounds__(512, 1) void fused_layer(
        const float* __restrict__ X, float* __restrict__ H,
        const float* __restrict__ Wl, const float* __restrict__ bl) {
    __shared__ float lds[LDSZ];
    float* const bufA = lds;
    float* const bufB = lds + FBUF;

    const int tid    = threadIdx.x;
    const int b      = blockIdx.x >> 4;
    const int ch     = blockIdx.x & (NCH - 1);
    const int T0     = ch * CHUNK;
    const int tw     = (T0 >= WARM) ? (T0 - WARM) : 0;
    const int tend   = T0 + CHUNK;                    // tend-tw = 16 or 22: even
    const int btbase = b * L_;

    // staging mapping (all 512 threads): x row r, 8 floats at col 8*l8
    const int r   = tid >> 3;                         // 0..63
    const int l8  = tid & 7;
    const int sx  = r + 1;                            // x slot
    const int vx  = (sx >> 1) & 7;
    const int dqx = l8 << 1;                          // data quads dqx, dqx+1
    // compute mapping: threads 0..503 -> output rows 0..62, 8 cols each
    const bool comp = tid < 504;
    const int  i    = r;                              // output row (when comp)
    const int  c0   = l8 << 3;
    const int  q0   = c0 >> 2;
    const int  sh   = 65 + i;                         // h-store slot (i<=61)
    const int  vh   = (sh >> 1) & 7;

    float w[9];
#pragma unroll
    for (int k = 0; k < 9; ++k) w[k] = Wl[k];
    const float bias = bl[0];
    const float4 z4 = make_float4(0.f, 0.f, 0.f, 0.f);

    // zero both frames: pads + slot 0 + h(-1)=0 (chunk 0); warm-up fixes rest
    for (int k = tid; k < LDSZ / 4; k += 512)
        reinterpret_cast<float4*>(lds)[k] = z4;
    __syncthreads();

    // stage x(tw) into bufA
    {
        const float* xg = X + (((size_t)(btbase + tw)) << 12) + (r << 6) + (l8 << 3);
        const float4 a0 = reinterpret_cast<const float4*>(xg)[0];
        const float4 a1 = reinterpret_cast<const float4*>(xg)[1];
        float* xd = bufA + sx * PITCH;
        *reinterpret_cast<float4*>(xd + (((dqx + 1) ^ vx) << 2)) = a0;
        *reinterpret_cast<float4*>(xd + (((dqx + 2) ^ vx) << 2)) = a1;
    }
    // register prefetch x(tw+1)
    float4 pa, pb;
    {
        const int t1 = (tw + 1 < L_) ? tw + 1 : L_ - 1;
        const float* xg = X + (((size_t)(btbase + t1)) << 12) + (r << 6) + (l8 << 3);
        pa = reinterpret_cast<const float4*>(xg)[0];
        pb = reinterpret_cast<const float4*>(xg)[1];
    }
    __syncthreads();

    auto STEP = [&](int t, float* cur, float* nxt) {
        // issue x(t+2) loads — 2 steps deep, latency fully off the chain
        const int t2 = (t + 2 < L_) ? t + 2 : L_ - 1;
        const float* xg = X + (((size_t)(btbase + t2)) << 12) + (r << 6) + (l8 << 3);
        const float4 na = reinterpret_cast<const float4*>(xg)[0];
        const float4 nb = reinterpret_cast<const float4*>(xg)[1];

        if (comp) {
            float acc[8];
#pragma unroll
            for (int k = 0; k < 8; ++k) acc[k] = bias;
#pragma unroll
            for (int ki = 0; ki < 3; ++ki) {
                const int s = 2 * i + ki;              // slot of concat row 2i-1+ki
                const int v = (s >> 1) & 7;
                const float* hb = cur + s * PITCH;
                float g[16];
#pragma unroll
                for (int k = 0; k < 4; ++k) {          // window quads q0-1..q0+2
                    const float4 t4 = *reinterpret_cast<const float4*>(
                        hb + (((q0 + k) ^ v) << 2));
                    g[k*4+0] = t4.x; g[k*4+1] = t4.y;
                    g[k*4+2] = t4.z; g[k*4+3] = t4.w;
                }
                const float wa = w[ki*3], wb = w[ki*3+1], wc = w[ki*3+2];
#pragma unroll
                for (int k = 0; k < 8; ++k)
                    acc[k] = fmaf(wa, g[k+3], fmaf(wb, g[k+4], fmaf(wc, g[k+5], acc[k])));
            }
            float o[8];
#pragma unroll
            for (int k = 0; k < 8; ++k) o[k] = ftanh(acc[k]);

            if (t >= T0) {                             // skip warm-up writes
                float* gd = H + (((size_t)(btbase + t)) << 12) + (i << 6) + c0;
                *reinterpret_cast<float4*>(gd)     = make_float4(o[0],o[1],o[2],o[3]);
                *reinterpret_cast<float4*>(gd + 4) = make_float4(o[4],o[5],o[6],o[7]);
            }
            if (i <= 61) {                             // h row for next step
                float* hd = nxt + sh * PITCH;
                *reinterpret_cast<float4*>(hd + (((q0+1) ^ vh) << 2)) =
                    make_float4(o[0],o[1],o[2],o[3]);
                *reinterpret_cast<float4*>(hd + (((q0+2) ^ vh) << 2)) =
                    make_float4(o[4],o[5],o[6],o[7]);
            }
        }
        {   // commit x(t+1) into nxt
            float* xd = nxt + sx * PITCH;
            *reinterpret_cast<float4*>(xd + (((dqx + 1) ^ vx) << 2)) = pa;
            *reinterpret_cast<float4*>(xd + (((dqx + 2) ^ vx) << 2)) = pb;
        }
        __syncthreads();
        pa = na; pb = nb;
    };

    for (int t = tw; t < tend; t += 2) {               // span always even
        STEP(t,     bufA, bufB);
        STEP(t + 1, bufB, bufA);
    }
}

// ---------------------------------------------------------------------------
// Sequential scan for row 63 (reads rows 61/62 from global, written above).
#define SDEPTH 16
__global__ void scan63(float* __restrict__ dst,
                       const float* __restrict__ src,
                       const float* __restrict__ Wl,
                       const float* __restrict__ bl) {
    const int b = blockIdx.x;
    const int j = threadIdx.x;                         // 0..63, one wave
    float w[9];
#pragma unroll
    for (int k = 0; k < 9; ++k) w[k] = Wl[k];
    const float bias = bl[0];

    const size_t ST = (size_t)D_ * D_;
    const float* s61 = src + (size_t)b * L_ * ST + 61 * 64 + j;
    const float* s62 = src + (size_t)b * L_ * ST + 62 * 64 + j;
    float*       d63 = dst + (size_t)b * L_ * ST + 63 * 64 + j;

    float s = ftanh(bias);                             // t=0: h_{-1}=0
    d63[0] = s;

    float p61[SDEPTH], p62[SDEPTH];
#pragma unroll
    for (int u = 0; u < SDEPTH; ++u) {
        p61[u] = s61[(size_t)u * ST];
        p62[u] = s62[(size_t)u * ST];
    }

    for (int t0 = 1; t0 < 256; t0 += SDEPTH) {
#pragma unroll
        for (int u = 0; u < SDEPTH; ++u) {
            const int t = t0 + u;
            if (t > 255) break;
            const float r61 = p61[u], r62 = p62[u];
            int tp = t + SDEPTH - 1;
            if (tp > 255) tp = 255;
            p61[u] = s61[(size_t)tp * ST];
            p62[u] = s62[(size_t)tp * ST];
            float l1 = dpp_shr1(r61), q1 = dpp_shl1(r61);
            float l2 = dpp_shr1(r62), q2 = dpp_shl1(r62);
            float p = bias;
            p = fmaf(w[0], l1, p); p = fmaf(w[1], r61, p); p = fmaf(w[2], q1, p);
            p = fmaf(w[3], l2, p); p = fmaf(w[4], r62, p); p = fmaf(w[5], q2, p);
            float ls = dpp_shr1(s), rs = dpp_shl1(s);
            float z = fmaf(w[6], ls, fmaf(w[7], s, fmaf(w[8], rs, p)));
            s = ftanh(z);
            d63[(size_t)t * ST] = s;
        }
    }
}

extern "C" void kernel_launch(void* const* d_in, const int* in_sizes, int n_in,
                              void* d_out, int out_size, void* d_ws, size_t ws_size,
                              hipStream_t stream) {
    const float* x    = (const float*)d_in[0];   // (B,L,D,D)
    const float* W    = (const float*)d_in[1];   // (2,1,1,3,3)
    const float* bias = (const float*)d_in[2];   // (2,)
    float* out = (float*)d_out;
    float* h1  = (float*)d_ws;

    for (int l = 0; l < 2; ++l) {
        const float* X  = (l == 0) ? x  : h1;
        float*       H  = (l == 0) ? h1 : out;
        fused_layer<<<B_ * NCH, 512, 0, stream>>>(X, H, W + l * 9, bias + l);
        scan63<<<B_, 64, 0, stream>>>(H, H, W + l * 9, bias + l);
    }
}